// Round 4
// baseline (445.171 us; speedup 1.0000x reference)
//
#include <hip/hip_runtime.h>

typedef __attribute__((ext_vector_type(8))) short bfrag8;   // 8 bf16 = 4 VGPRs
typedef __attribute__((ext_vector_type(4))) float f32x4v;   // MFMA acc

__device__ inline short f2bf(float f) {
    unsigned u = __builtin_bit_cast(unsigned, f);
    u = (u + 0x7FFFu + ((u >> 16) & 1u)) >> 16;
    return (short)u;
}
__device__ inline float bf2f(short s) {
    unsigned u = ((unsigned)(unsigned short)s) << 16;
    return __builtin_bit_cast(float, u);
}
__device__ inline int pack2(short lo, short hi) {
    return (int)(((unsigned)(unsigned short)lo) | (((unsigned)(unsigned short)hi) << 16));
}
__device__ inline void gload_lds16(const short* g, short* l) {
    __builtin_amdgcn_global_load_lds(
        (const __attribute__((address_space(1))) void*)g,
        (__attribute__((address_space(3))) void*)l, 16, 0, 0);
}

// ---------------- CSR construction ----------------

__global__ void deg_count_kernel(const int* __restrict__ dst, int E, int* __restrict__ deg) {
    int e = blockIdx.x * blockDim.x + threadIdx.x;
    if (e < E) atomicAdd(&deg[dst[e]], 1);
}

__global__ void block_sum_kernel(const int* __restrict__ deg, int n, int* __restrict__ bsums) {
    int i = blockIdx.x * 256 + threadIdx.x;
    int v = (i < n) ? deg[i] : 0;
#pragma unroll
    for (int off = 32; off > 0; off >>= 1) v += __shfl_down(v, off);
    __shared__ int wsum[4];
    int lane = threadIdx.x & 63, w = threadIdx.x >> 6;
    if (lane == 0) wsum[w] = v;
    __syncthreads();
    if (threadIdx.x == 0) bsums[blockIdx.x] = wsum[0] + wsum[1] + wsum[2] + wsum[3];
}

__global__ void scan_bsums_kernel(int* __restrict__ bsums, int B, int* __restrict__ offs, int n) {
    __shared__ int s[256];
    int tid = threadIdx.x;
    int v = (tid < B) ? bsums[tid] : 0;
    s[tid] = v;
    __syncthreads();
    for (int off = 1; off < 256; off <<= 1) {
        int t = (tid >= off) ? s[tid - off] : 0;
        __syncthreads();
        s[tid] += t;
        __syncthreads();
    }
    if (tid < B) bsums[tid] = (tid == 0) ? 0 : s[tid - 1];
    if (tid == 0) offs[n] = s[255];
}

__global__ void scan_final_kernel(const int* __restrict__ deg, int n,
                                  const int* __restrict__ bsums,
                                  int* __restrict__ offs, int* __restrict__ cursor,
                                  float* __restrict__ dinv) {
    __shared__ int s[256];
    int tid = threadIdx.x;
    int i = blockIdx.x * 256 + tid;
    int v = (i < n) ? deg[i] : 0;
    s[tid] = v;
    __syncthreads();
    for (int off = 1; off < 256; off <<= 1) {
        int t = (tid >= off) ? s[tid - off] : 0;
        __syncthreads();
        s[tid] += t;
        __syncthreads();
    }
    if (i < n) {
        int excl = s[tid] - v + bsums[blockIdx.x];
        offs[i] = excl;
        cursor[i] = excl;
        dinv[i] = rsqrtf((float)(v + 1));
    }
}

__global__ void csr_fill_kernel(const int* __restrict__ src, const int* __restrict__ dst, int E,
                                int* __restrict__ cursor, int* __restrict__ csr) {
    int e = blockIdx.x * blockDim.x + threadIdx.x;
    if (e < E) {
        int d = dst[e];
        int p = atomicAdd(&cursor[d], 1);
        csr[p] = src[e];
    }
}

// ---------------- weight transpose + bf16: Wt[n][k] = bf16(W[k][n]) ----------------

__global__ void wt_kernel(const float* __restrict__ W, short* __restrict__ Wt,
                          int K, int logN) {
    int i = blockIdx.x * blockDim.x + threadIdx.x;
    int total = K << logN;
    if (i < total) {
        int k = i >> logN;
        int n = i & ((1 << logN) - 1);
        Wt[(size_t)n * K + k] = f2bf(W[i]);
    }
}

// ---------------- x -> bf16 (8 elems/thread) ----------------

__global__ void x2b_kernel(const float* __restrict__ x, short* __restrict__ xb, int total8) {
    int i = blockIdx.x * blockDim.x + threadIdx.x;
    if (i < total8) {
        const float4* p = (const float4*)(x + (size_t)i * 8);
        float4 v0 = p[0], v1 = p[1];
        int4 w = make_int4(pack2(f2bf(v0.x), f2bf(v0.y)), pack2(f2bf(v0.z), f2bf(v0.w)),
                           pack2(f2bf(v1.x), f2bf(v1.y)), pack2(f2bf(v1.z), f2bf(v1.w)));
        *(int4*)(xb + (size_t)i * 8) = w;
    }
}

// ---------------- bf16 MFMA GEMM (m97-style): Tout = bf16((A@Bt^T) * dinv[row]) ----------------
// A: bf16 [Mpad][lda] (rows padded, no bounds checks). Bt: bf16 [N][K].
// Tile 128x128, BK=32, LDS [128][32] unpadded, staged with global_load_lds width=16.

__global__ __launch_bounds__(256) void gemm_bf16_kernel(
        const short* __restrict__ A, int lda,
        const short* __restrict__ Bt, int K,
        const float* __restrict__ dinv,
        short* __restrict__ Tout, int ldt,
        int M) {
    __shared__ short As[128 * 32];
    __shared__ short Bs[128 * 32];

    const int tid = threadIdx.x;
    const int lane = tid & 63;
    const int wid = tid >> 6;
    const int l15 = lane & 15;
    const int quad = lane >> 4;
    const int q8 = quad * 8;
    const int bm = blockIdx.x * 128;
    const int bn = blockIdx.y * 128;
    const int wm = (wid & 1) * 64;
    const int wn = (wid >> 1) * 64;

    f32x4v acc[4][4];
#pragma unroll
    for (int i = 0; i < 4; ++i)
#pragma unroll
        for (int j = 0; j < 4; ++j) acc[i][j] = (f32x4v){0.f, 0.f, 0.f, 0.f};

    // staging map: LDS byte offset o = wid*2048 + i*1024 + lane*16 -> row o/64, k (o%64)/2
    const int f0 = wid * 2048 + lane * 16;
    const int r0 = f0 >> 6, c0 = (f0 & 63) >> 1;
    const int f1 = f0 + 1024;
    const int r1 = f1 >> 6, c1 = (f1 & 63) >> 1;
    short* ldsA = As + wid * 1024;           // shorts
    short* ldsB = Bs + wid * 1024;

    const short* a0 = A + (size_t)(bm + r0) * lda + c0;
    const short* a1 = A + (size_t)(bm + r1) * lda + c1;
    const short* b0 = Bt + (size_t)(bn + r0) * K + c0;
    const short* b1 = Bt + (size_t)(bn + r1) * K + c1;

    for (int k0 = 0; k0 < K; k0 += 32) {
        gload_lds16(a0 + k0, ldsA);
        gload_lds16(a1 + k0, ldsA + 512);
        gload_lds16(b0 + k0, ldsB);
        gload_lds16(b1 + k0, ldsB + 512);
        __syncthreads();

        bfrag8 af[4], bfv[4];
#pragma unroll
        for (int mt = 0; mt < 4; ++mt)
            af[mt] = *(const bfrag8*)&As[(wm + mt * 16 + l15) * 32 + q8];
#pragma unroll
        for (int nt = 0; nt < 4; ++nt)
            bfv[nt] = *(const bfrag8*)&Bs[(wn + nt * 16 + l15) * 32 + q8];
#pragma unroll
        for (int mt = 0; mt < 4; ++mt)
#pragma unroll
            for (int nt = 0; nt < 4; ++nt)
                acc[mt][nt] = __builtin_amdgcn_mfma_f32_16x16x32_bf16(af[mt], bfv[nt], acc[mt][nt], 0, 0, 0);
        __syncthreads();
    }

#pragma unroll
    for (int mt = 0; mt < 4; ++mt) {
#pragma unroll
        for (int r = 0; r < 4; ++r) {
            int grow = bm + wm + mt * 16 + quad * 4 + r;
            if (grow < M) {
                float di = dinv[grow];
                short* outp = Tout + (size_t)grow * ldt + bn + wn + l15;
#pragma unroll
                for (int nt = 0; nt < 4; ++nt)
                    outp[nt * 16] = f2bf(acc[mt][nt][r] * di);
            }
        }
    }
}

// ---------------- Aggregation ----------------
// out[d] = relu(dinv[d]*(sum_{s in N(d)} hn[s] + hn[d]) + b); optional bf16 copy to hb.

template<int C, bool WB>
__global__ __launch_bounds__(256) void agg_kernel(
        const short* __restrict__ hn, const float* __restrict__ dinv,
        const int* __restrict__ offs, const int* __restrict__ csr,
        const float* __restrict__ bias, float* __restrict__ out,
        short* __restrict__ hb, int coloff, int n) {
    constexpr int V = C / 64;
    int node = blockIdx.x * 4 + (threadIdx.x >> 6);
    if (node >= n) return;
    int lane = threadIdx.x & 63;
    const short* base = hn + lane * V;

    float acc[V];
#pragma unroll
    for (int v = 0; v < V; ++v) acc[v] = 0.f;

    int beg = offs[node], end = offs[node + 1];
    int e = beg;
    if (V == 4) {
        for (; e + 8 <= end; e += 8) {
            short4 r[8];
#pragma unroll
            for (int j = 0; j < 8; ++j)
                r[j] = *(const short4*)(base + (size_t)csr[e + j] * C);
#pragma unroll
            for (int j = 0; j < 8; ++j) {
                acc[0] += bf2f(r[j].x); acc[1] += bf2f(r[j].y);
                acc[2] += bf2f(r[j].z); acc[3] += bf2f(r[j].w);
            }
        }
        for (; e < end; ++e) {
            short4 a = *(const short4*)(base + (size_t)csr[e] * C);
            acc[0] += bf2f(a.x); acc[1] += bf2f(a.y); acc[2] += bf2f(a.z); acc[3] += bf2f(a.w);
        }
        short4 a = *(const short4*)(base + (size_t)node * C);  // self loop
        acc[0] += bf2f(a.x); acc[1] += bf2f(a.y); acc[2] += bf2f(a.z); acc[3] += bf2f(a.w);
    } else {
        for (; e + 8 <= end; e += 8) {
            short2 r[8];
#pragma unroll
            for (int j = 0; j < 8; ++j)
                r[j] = *(const short2*)(base + (size_t)csr[e + j] * C);
#pragma unroll
            for (int j = 0; j < 8; ++j) {
                acc[0] += bf2f(r[j].x); acc[1] += bf2f(r[j].y);
            }
        }
        for (; e < end; ++e) {
            short2 a = *(const short2*)(base + (size_t)csr[e] * C);
            acc[0] += bf2f(a.x); acc[1] += bf2f(a.y);
        }
        short2 a = *(const short2*)(base + (size_t)node * C);
        acc[0] += bf2f(a.x); acc[1] += bf2f(a.y);
    }

    float di = dinv[node];
    float res[V];
#pragma unroll
    for (int v = 0; v < V; ++v)
        res[v] = fmaxf(fmaf(di, acc[v], bias[lane * V + v]), 0.f);

    float* op = out + (size_t)node * 512 + coloff + lane * V;
    if (V == 4) {
        *(float4*)op = make_float4(res[0], res[1], res[2], res[3]);
        if (WB) {
            int2 w = make_int2(pack2(f2bf(res[0]), f2bf(res[1])), pack2(f2bf(res[2]), f2bf(res[3])));
            *(int2*)(hb + (size_t)node * C + lane * V) = w;
        }
    } else {
        *(float2*)op = make_float2(res[0], res[1]);
        if (WB) {
            *(int*)(hb + (size_t)node * C + lane * V) = pack2(f2bf(res[0]), f2bf(res[1]));
        }
    }
}

// ---------------- launch ----------------

extern "C" void kernel_launch(void* const* d_in, const int* in_sizes, int n_in,
                              void* d_out, int out_size, void* d_ws, size_t ws_size,
                              hipStream_t stream) {
    const float* x  = (const float*)d_in[0];
    const int*   ei = (const int*)d_in[1];
    const float* W1 = (const float*)d_in[2];
    const float* b1 = (const float*)d_in[3];
    const float* W2 = (const float*)d_in[4];
    const float* b2 = (const float*)d_in[5];
    const float* W3 = (const float*)d_in[6];
    const float* b3 = (const float*)d_in[7];

    const int IN_C = 256, H2 = 256, H1 = 128, OUT_C = 128;
    int n = in_sizes[0] / IN_C;   // 50000
    int E = in_sizes[1] / 2;      // 800000
    const int* src = ei;
    const int* dst = ei + E;

    int mb = (n + 127) / 128;     // 391
    int npad = mb * 128;          // 50048 (padded rows: no staging bounds checks)

    char* ws = (char*)d_ws;
    auto carve = [&](size_t bytes) { char* p = ws; ws += (bytes + 255) & ~(size_t)255; return p; };
    int*   deg    = (int*)  carve((size_t)n * 4);
    int*   offs   = (int*)  carve(((size_t)n + 1) * 4);
    int*   cursor = (int*)  carve((size_t)n * 4);
    float* dinv   = (float*)carve((size_t)n * 4);
    int*   csr    = (int*)  carve((size_t)E * 4);
    int*   bsums  = (int*)  carve(256 * 4);
    short* Wt1    = (short*)carve((size_t)IN_C * H2 * 2);
    short* Wt2    = (short*)carve((size_t)H2 * H1 * 2);
    short* Wt3    = (short*)carve((size_t)H1 * OUT_C * 2);
    short* t      = (short*)carve((size_t)npad * 256 * 2);
    short* inb    = (short*)carve((size_t)npad * 256 * 2);  // xb -> h1b -> h2b (serial reuse)

    float* out = (float*)d_out;
    int nblk = (n + 255) / 256;

    hipMemsetAsync(deg, 0, (size_t)n * sizeof(int), stream);
    deg_count_kernel<<<(E + 255) / 256, 256, 0, stream>>>(dst, E, deg);
    block_sum_kernel<<<nblk, 256, 0, stream>>>(deg, n, bsums);
    scan_bsums_kernel<<<1, 256, 0, stream>>>(bsums, nblk, offs, n);
    scan_final_kernel<<<nblk, 256, 0, stream>>>(deg, n, bsums, offs, cursor, dinv);
    csr_fill_kernel<<<(E + 255) / 256, 256, 0, stream>>>(src, dst, E, cursor, csr);

    wt_kernel<<<(IN_C * H2 + 255) / 256, 256, 0, stream>>>(W1, Wt1, IN_C, 8);
    wt_kernel<<<(H2 * H1 + 255) / 256, 256, 0, stream>>>(W2, Wt2, H2, 7);
    wt_kernel<<<(H1 * OUT_C + 255) / 256, 256, 0, stream>>>(W3, Wt3, H1, 7);

    int total8 = n * IN_C / 8;
    x2b_kernel<<<(total8 + 255) / 256, 256, 0, stream>>>(x, inb, total8);

    // Layer 1: t = bf16((x@W1)*dinv); agg -> out[:,0:256] + h1b
    gemm_bf16_kernel<<<dim3(mb, H2 / 128), 256, 0, stream>>>(inb, IN_C, Wt1, IN_C, dinv, t, H2, n);
    agg_kernel<256, true><<<(n + 3) / 4, 256, 0, stream>>>(t, dinv, offs, csr, b1, out, inb, 0, n);

    // Layer 2: t = bf16((h1@W2)*dinv); agg -> out[:,256:384] + h2b
    gemm_bf16_kernel<<<dim3(mb, H1 / 128), 256, 0, stream>>>(inb, H2, Wt2, H2, dinv, t, H1, n);
    agg_kernel<128, true><<<(n + 3) / 4, 256, 0, stream>>>(t, dinv, offs, csr, b2, out, inb, H2, n);

    // Layer 3: t = bf16((h2@W3)*dinv); agg -> out[:,384:512]
    gemm_bf16_kernel<<<dim3(mb, OUT_C / 128), 256, 0, stream>>>(inb, H1, Wt3, H1, dinv, t, OUT_C, n);
    agg_kernel<128, false><<<(n + 3) / 4, 256, 0, stream>>>(t, dinv, offs, csr, b3, out, nullptr, H2 + H1, n);
}

// Round 5
// 443.058 us; speedup vs baseline: 1.0048x; 1.0048x over previous
//
#include <hip/hip_runtime.h>

typedef __attribute__((ext_vector_type(8))) short bfrag8;   // 8 bf16 = 4 VGPRs
typedef __attribute__((ext_vector_type(4))) float f32x4v;   // MFMA acc

__device__ inline short f2bf(float f) {
    unsigned u = __builtin_bit_cast(unsigned, f);
    u = (u + 0x7FFFu + ((u >> 16) & 1u)) >> 16;
    return (short)u;
}
__device__ inline float bf2f(short s) {
    unsigned u = ((unsigned)(unsigned short)s) << 16;
    return __builtin_bit_cast(float, u);
}
__device__ inline int pack2(short lo, short hi) {
    return (int)(((unsigned)(unsigned short)lo) | (((unsigned)(unsigned short)hi) << 16));
}

// ---------------- CSR construction ----------------

__global__ void deg_count_kernel(const int* __restrict__ dst, int E, int* __restrict__ deg) {
    int e = blockIdx.x * blockDim.x + threadIdx.x;
    if (e < E) atomicAdd(&deg[dst[e]], 1);
}

__global__ void block_sum_kernel(const int* __restrict__ deg, int n, int* __restrict__ bsums) {
    int i = blockIdx.x * 256 + threadIdx.x;
    int v = (i < n) ? deg[i] : 0;
#pragma unroll
    for (int off = 32; off > 0; off >>= 1) v += __shfl_down(v, off);
    __shared__ int wsum[4];
    int lane = threadIdx.x & 63, w = threadIdx.x >> 6;
    if (lane == 0) wsum[w] = v;
    __syncthreads();
    if (threadIdx.x == 0) bsums[blockIdx.x] = wsum[0] + wsum[1] + wsum[2] + wsum[3];
}

__global__ void scan_bsums_kernel(int* __restrict__ bsums, int B, int* __restrict__ offs, int n) {
    __shared__ int s[256];
    int tid = threadIdx.x;
    int v = (tid < B) ? bsums[tid] : 0;
    s[tid] = v;
    __syncthreads();
    for (int off = 1; off < 256; off <<= 1) {
        int t = (tid >= off) ? s[tid - off] : 0;
        __syncthreads();
        s[tid] += t;
        __syncthreads();
    }
    if (tid < B) bsums[tid] = (tid == 0) ? 0 : s[tid - 1];
    if (tid == 0) offs[n] = s[255];
}

__global__ void scan_final_kernel(const int* __restrict__ deg, int n,
                                  const int* __restrict__ bsums,
                                  int* __restrict__ offs, int* __restrict__ cursor,
                                  float* __restrict__ dinv) {
    __shared__ int s[256];
    int tid = threadIdx.x;
    int i = blockIdx.x * 256 + tid;
    int v = (i < n) ? deg[i] : 0;
    s[tid] = v;
    __syncthreads();
    for (int off = 1; off < 256; off <<= 1) {
        int t = (tid >= off) ? s[tid - off] : 0;
        __syncthreads();
        s[tid] += t;
        __syncthreads();
    }
    if (i < n) {
        int excl = s[tid] - v + bsums[blockIdx.x];
        offs[i] = excl;
        cursor[i] = excl;
        dinv[i] = rsqrtf((float)(v + 1));
    }
}

__global__ void csr_fill_kernel(const int* __restrict__ src, const int* __restrict__ dst, int E,
                                int* __restrict__ cursor, int* __restrict__ csr) {
    int e = blockIdx.x * blockDim.x + threadIdx.x;
    if (e < E) {
        int d = dst[e];
        int p = atomicAdd(&cursor[d], 1);
        csr[p] = src[e];
    }
}

// ---------------- weight transpose + bf16: Wt[n][k] = bf16(W[k][n]) ----------------

__global__ void wt_kernel(const float* __restrict__ W, short* __restrict__ Wt,
                          int K, int logN) {
    int i = blockIdx.x * blockDim.x + threadIdx.x;
    int total = K << logN;
    if (i < total) {
        int k = i >> logN;
        int n = i & ((1 << logN) - 1);
        Wt[(size_t)n * K + k] = f2bf(W[i]);
    }
}

// ---------------- x -> bf16 (8 elems/thread) ----------------

__global__ void x2b_kernel(const float* __restrict__ x, short* __restrict__ xb, int total8) {
    int i = blockIdx.x * blockDim.x + threadIdx.x;
    if (i < total8) {
        const float4* p = (const float4*)(x + (size_t)i * 8);
        float4 v0 = p[0], v1 = p[1];
        int4 w = make_int4(pack2(f2bf(v0.x), f2bf(v0.y)), pack2(f2bf(v0.z), f2bf(v0.w)),
                           pack2(f2bf(v1.x), f2bf(v1.y)), pack2(f2bf(v1.z), f2bf(v1.w)));
        *(int4*)(xb + (size_t)i * 8) = w;
    }
}

// ---------------- tall-skinny bf16 MFMA GEMM ----------------
// Tout[m][bn+j] = bf16((A[m,:] @ Bt[bn+j,:]) * dinv[m]).
// B slice (64 cols x K) staged in LDS ONCE; A fragments loaded global->VGPR directly.
// NO barriers in the K-loop. Each wave: 64 rows x 64 cols. Grid: (npad/256, N/64).
// Buffers row-padded to npad -> no bounds checks anywhere.

template<int K>
__global__ __launch_bounds__(256, 2) void gemm_skinny_kernel(
        const short* __restrict__ A,     // [npad][K]
        const short* __restrict__ Bt,    // [N][K]
        const float* __restrict__ dinv,  // [npad]
        short* __restrict__ Tout, int ldt) {
    constexpr int BSTR = K + 8;          // padded row stride: bank-conflict-free
    __shared__ short Bs[64 * BSTR];

    const int tid = threadIdx.x;
    const int lane = tid & 63;
    const int wid = tid >> 6;
    const int l15 = lane & 15;
    const int quad = lane >> 4;
    const int q8 = quad * 8;
    const int bn = blockIdx.y * 64;
    const int row0 = blockIdx.x * 256 + wid * 64;

    // Stage B slice: 64 rows x K shorts, int4 strided copy.
    {
        constexpr int TOT16 = 64 * K / 8;  // # of int4 chunks (2048 for K=256)
#pragma unroll
        for (int i = tid; i < TOT16; i += 256) {
            int r = i / (K / 8);
            int c = (i % (K / 8)) * 8;
            *(int4*)&Bs[r * BSTR + c] = *(const int4*)&Bt[(size_t)(bn + r) * K + c];
        }
    }
    __syncthreads();

    f32x4v acc[4][4];
#pragma unroll
    for (int i = 0; i < 4; ++i)
#pragma unroll
        for (int j = 0; j < 4; ++j) acc[i][j] = (f32x4v){0.f, 0.f, 0.f, 0.f};

    const short* aBase = A + (size_t)(row0 + l15) * K + q8;

#pragma unroll
    for (int ks = 0; ks < K / 32; ++ks) {
        bfrag8 af[4], bf[4];
#pragma unroll
        for (int mt = 0; mt < 4; ++mt)
            af[mt] = *(const bfrag8*)(aBase + (size_t)mt * 16 * K + ks * 32);
#pragma unroll
        for (int nt = 0; nt < 4; ++nt)
            bf[nt] = *(const bfrag8*)&Bs[(nt * 16 + l15) * BSTR + ks * 32 + q8];
#pragma unroll
        for (int mt = 0; mt < 4; ++mt)
#pragma unroll
            for (int nt = 0; nt < 4; ++nt)
                acc[mt][nt] = __builtin_amdgcn_mfma_f32_16x16x32_bf16(af[mt], bf[nt], acc[mt][nt], 0, 0, 0);
    }

    // Epilogue: scale by dinv[row], cvt bf16, store (rows padded -> no guards).
#pragma unroll
    for (int mt = 0; mt < 4; ++mt) {
#pragma unroll
        for (int r = 0; r < 4; ++r) {
            int grow = row0 + mt * 16 + quad * 4 + r;
            float di = dinv[grow];
            short* outp = Tout + (size_t)grow * ldt + bn + l15;
#pragma unroll
            for (int nt = 0; nt < 4; ++nt)
                outp[nt * 16] = f2bf(acc[mt][nt][r] * di);
        }
    }
}

// ---------------- Aggregation ----------------
// out[d] = relu(dinv[d]*(sum_{s in N(d)} hn[s] + hn[d]) + b); optional bf16 copy to hb.

template<int C, bool WB>
__global__ __launch_bounds__(256) void agg_kernel(
        const short* __restrict__ hn, const float* __restrict__ dinv,
        const int* __restrict__ offs, const int* __restrict__ csr,
        const float* __restrict__ bias, float* __restrict__ out,
        short* __restrict__ hb, int coloff, int n) {
    constexpr int V = C / 64;
    int node = blockIdx.x * 4 + (threadIdx.x >> 6);
    if (node >= n) return;
    int lane = threadIdx.x & 63;
    const short* base = hn + lane * V;

    float acc[V];
#pragma unroll
    for (int v = 0; v < V; ++v) acc[v] = 0.f;

    int beg = offs[node], end = offs[node + 1];
    int e = beg;
    if (V == 4) {
        for (; e + 8 <= end; e += 8) {
            short4 r[8];
#pragma unroll
            for (int j = 0; j < 8; ++j)
                r[j] = *(const short4*)(base + (size_t)csr[e + j] * C);
#pragma unroll
            for (int j = 0; j < 8; ++j) {
                acc[0] += bf2f(r[j].x); acc[1] += bf2f(r[j].y);
                acc[2] += bf2f(r[j].z); acc[3] += bf2f(r[j].w);
            }
        }
        for (; e < end; ++e) {
            short4 a = *(const short4*)(base + (size_t)csr[e] * C);
            acc[0] += bf2f(a.x); acc[1] += bf2f(a.y); acc[2] += bf2f(a.z); acc[3] += bf2f(a.w);
        }
        short4 a = *(const short4*)(base + (size_t)node * C);  // self loop
        acc[0] += bf2f(a.x); acc[1] += bf2f(a.y); acc[2] += bf2f(a.z); acc[3] += bf2f(a.w);
    } else {
        for (; e + 8 <= end; e += 8) {
            short2 r[8];
#pragma unroll
            for (int j = 0; j < 8; ++j)
                r[j] = *(const short2*)(base + (size_t)csr[e + j] * C);
#pragma unroll
            for (int j = 0; j < 8; ++j) {
                acc[0] += bf2f(r[j].x); acc[1] += bf2f(r[j].y);
            }
        }
        for (; e < end; ++e) {
            short2 a = *(const short2*)(base + (size_t)csr[e] * C);
            acc[0] += bf2f(a.x); acc[1] += bf2f(a.y);
        }
        short2 a = *(const short2*)(base + (size_t)node * C);
        acc[0] += bf2f(a.x); acc[1] += bf2f(a.y);
    }

    float di = dinv[node];
    float res[V];
#pragma unroll
    for (int v = 0; v < V; ++v)
        res[v] = fmaxf(fmaf(di, acc[v], bias[lane * V + v]), 0.f);

    float* op = out + (size_t)node * 512 + coloff + lane * V;
    if (V == 4) {
        *(float4*)op = make_float4(res[0], res[1], res[2], res[3]);
        if (WB) {
            int2 w = make_int2(pack2(f2bf(res[0]), f2bf(res[1])), pack2(f2bf(res[2]), f2bf(res[3])));
            *(int2*)(hb + (size_t)node * C + lane * V) = w;
        }
    } else {
        *(float2*)op = make_float2(res[0], res[1]);
        if (WB) {
            *(int*)(hb + (size_t)node * C + lane * V) = pack2(f2bf(res[0]), f2bf(res[1]));
        }
    }
}

// ---------------- launch ----------------

extern "C" void kernel_launch(void* const* d_in, const int* in_sizes, int n_in,
                              void* d_out, int out_size, void* d_ws, size_t ws_size,
                              hipStream_t stream) {
    const float* x  = (const float*)d_in[0];
    const int*   ei = (const int*)d_in[1];
    const float* W1 = (const float*)d_in[2];
    const float* b1 = (const float*)d_in[3];
    const float* W2 = (const float*)d_in[4];
    const float* b2 = (const float*)d_in[5];
    const float* W3 = (const float*)d_in[6];
    const float* b3 = (const float*)d_in[7];

    const int IN_C = 256, H2 = 256, H1 = 128, OUT_C = 128;
    int n = in_sizes[0] / IN_C;   // 50000
    int E = in_sizes[1] / 2;      // 800000
    const int* src = ei;
    const int* dst = ei + E;

    int sb = (n + 255) / 256;     // 196 row stripes of 256
    int npad = sb * 256;          // 50176 padded rows

    char* ws = (char*)d_ws;
    auto carve = [&](size_t bytes) { char* p = ws; ws += (bytes + 255) & ~(size_t)255; return p; };
    int*   deg    = (int*)  carve((size_t)n * 4);
    int*   offs   = (int*)  carve(((size_t)n + 1) * 4);
    int*   cursor = (int*)  carve((size_t)n * 4);
    float* dinv   = (float*)carve((size_t)npad * 4);
    int*   csr    = (int*)  carve((size_t)E * 4);
    int*   bsums  = (int*)  carve(256 * 4);
    short* Wt1    = (short*)carve((size_t)IN_C * H2 * 2);
    short* Wt2    = (short*)carve((size_t)H2 * H1 * 2);
    short* Wt3    = (short*)carve((size_t)H1 * OUT_C * 2);
    short* t      = (short*)carve((size_t)npad * 256 * 2);
    short* inb    = (short*)carve((size_t)npad * 256 * 2);  // xb -> h1b -> h2b (serial reuse)

    float* out = (float*)d_out;
    int nblk = (n + 255) / 256;

    hipMemsetAsync(deg, 0, (size_t)n * sizeof(int), stream);
    deg_count_kernel<<<(E + 255) / 256, 256, 0, stream>>>(dst, E, deg);
    block_sum_kernel<<<nblk, 256, 0, stream>>>(deg, n, bsums);
    scan_bsums_kernel<<<1, 256, 0, stream>>>(bsums, nblk, offs, n);
    scan_final_kernel<<<nblk, 256, 0, stream>>>(deg, n, bsums, offs, cursor, dinv);
    csr_fill_kernel<<<(E + 255) / 256, 256, 0, stream>>>(src, dst, E, cursor, csr);

    wt_kernel<<<(IN_C * H2 + 255) / 256, 256, 0, stream>>>(W1, Wt1, IN_C, 8);
    wt_kernel<<<(H2 * H1 + 255) / 256, 256, 0, stream>>>(W2, Wt2, H2, 7);
    wt_kernel<<<(H1 * OUT_C + 255) / 256, 256, 0, stream>>>(W3, Wt3, H1, 7);

    int total8 = n * IN_C / 8;
    x2b_kernel<<<(total8 + 255) / 256, 256, 0, stream>>>(x, inb, total8);

    // Layer 1: t = bf16((x@W1)*dinv); agg -> out[:,0:256] + h1b
    gemm_skinny_kernel<256><<<dim3(sb, H2 / 64), 256, 0, stream>>>(inb, Wt1, dinv, t, H2);
    agg_kernel<256, true><<<(n + 3) / 4, 256, 0, stream>>>(t, dinv, offs, csr, b1, out, inb, 0, n);

    // Layer 2 (K=256): t = bf16((h1@W2)*dinv); agg -> out[:,256:384] + h2b
    gemm_skinny_kernel<256><<<dim3(sb, H1 / 64), 256, 0, stream>>>(inb, Wt2, dinv, t, H1);
    agg_kernel<128, true><<<(n + 3) / 4, 256, 0, stream>>>(t, dinv, offs, csr, b2, out, inb, H2, n);

    // Layer 3 (K=128): t = bf16((h2@W3)*dinv); agg -> out[:,384:512]
    gemm_skinny_kernel<128><<<dim3(sb, OUT_C / 64), 256, 0, stream>>>(inb, Wt3, dinv, t, OUT_C);
    agg_kernel<128, false><<<(n + 3) / 4, 256, 0, stream>>>(t, dinv, offs, csr, b3, out, nullptr, H2 + H1, n);
}

// Round 6
// 430.206 us; speedup vs baseline: 1.0348x; 1.0299x over previous
//
#include <hip/hip_runtime.h>

typedef __attribute__((ext_vector_type(8))) short bfrag8;   // 8 bf16 = 4 VGPRs
typedef __attribute__((ext_vector_type(4))) float f32x4v;   // MFMA acc

__device__ inline short f2bf(float f) {
    unsigned u = __builtin_bit_cast(unsigned, f);
    u = (u + 0x7FFFu + ((u >> 16) & 1u)) >> 16;
    return (short)u;
}
__device__ inline float bf2f(short s) {
    unsigned u = ((unsigned)(unsigned short)s) << 16;
    return __builtin_bit_cast(float, u);
}
__device__ inline int pack2(short lo, short hi) {
    return (int)(((unsigned)(unsigned short)lo) | (((unsigned)(unsigned short)hi) << 16));
}

// ---------------- CSR construction ----------------

__global__ void deg_count_kernel(const int* __restrict__ dst, int E, int* __restrict__ deg) {
    int e = blockIdx.x * blockDim.x + threadIdx.x;
    if (e < E) atomicAdd(&deg[dst[e]], 1);
}

__global__ void block_sum_kernel(const int* __restrict__ deg, int n, int* __restrict__ bsums) {
    int i = blockIdx.x * 256 + threadIdx.x;
    int v = (i < n) ? deg[i] : 0;
#pragma unroll
    for (int off = 32; off > 0; off >>= 1) v += __shfl_down(v, off);
    __shared__ int wsum[4];
    int lane = threadIdx.x & 63, w = threadIdx.x >> 6;
    if (lane == 0) wsum[w] = v;
    __syncthreads();
    if (threadIdx.x == 0) bsums[blockIdx.x] = wsum[0] + wsum[1] + wsum[2] + wsum[3];
}

__global__ void scan_bsums_kernel(int* __restrict__ bsums, int B, int* __restrict__ offs, int n) {
    __shared__ int s[256];
    int tid = threadIdx.x;
    int v = (tid < B) ? bsums[tid] : 0;
    s[tid] = v;
    __syncthreads();
    for (int off = 1; off < 256; off <<= 1) {
        int t = (tid >= off) ? s[tid - off] : 0;
        __syncthreads();
        s[tid] += t;
        __syncthreads();
    }
    if (tid < B) bsums[tid] = (tid == 0) ? 0 : s[tid - 1];
    if (tid == 0) offs[n] = s[255];
}

__global__ void scan_final_kernel(const int* __restrict__ deg, int n,
                                  const int* __restrict__ bsums,
                                  int* __restrict__ offs, int* __restrict__ cursor,
                                  float* __restrict__ dinv) {
    __shared__ int s[256];
    int tid = threadIdx.x;
    int i = blockIdx.x * 256 + tid;
    int v = (i < n) ? deg[i] : 0;
    s[tid] = v;
    __syncthreads();
    for (int off = 1; off < 256; off <<= 1) {
        int t = (tid >= off) ? s[tid - off] : 0;
        __syncthreads();
        s[tid] += t;
        __syncthreads();
    }
    if (i < n) {
        int excl = s[tid] - v + bsums[blockIdx.x];
        offs[i] = excl;
        cursor[i] = excl;
        dinv[i] = rsqrtf((float)(v + 1));
    }
}

__global__ void csr_fill_kernel(const int* __restrict__ src, const int* __restrict__ dst, int E,
                                int* __restrict__ cursor, int* __restrict__ csr) {
    int e = blockIdx.x * blockDim.x + threadIdx.x;
    if (e < E) {
        int d = dst[e];
        int p = atomicAdd(&cursor[d], 1);
        csr[p] = src[e];
    }
}

// ---------------- fused weight transpose+bf16 for all 3 layers ----------------
// Wt[n][k] = bf16(W[k][n]). Segments: W1 256x256, W2 256x128, W3 128x128.

__global__ void prep_w_kernel(const float* __restrict__ W1, short* __restrict__ Wt1,
                              const float* __restrict__ W2, short* __restrict__ Wt2,
                              const float* __restrict__ W3, short* __restrict__ Wt3) {
    int i = blockIdx.x * blockDim.x + threadIdx.x;
    if (i < 65536) {                       // W1: K=256, N=256
        int k = i >> 8, n = i & 255;
        Wt1[n * 256 + k] = f2bf(W1[i]);
    } else if (i < 65536 + 32768) {        // W2: K=256, N=128
        int j = i - 65536;
        int k = j >> 7, n = j & 127;
        Wt2[n * 256 + k] = f2bf(W2[j]);
    } else {                               // W3: K=128, N=128
        int j = i - 65536 - 32768;
        int k = j >> 7, n = j & 127;
        Wt3[n * 128 + k] = f2bf(W3[j]);
    }
}

// ---------------- x -> bf16 (8 elems/thread) ----------------

__global__ void x2b_kernel(const float* __restrict__ x, short* __restrict__ xb, int total8) {
    int i = blockIdx.x * blockDim.x + threadIdx.x;
    if (i < total8) {
        const float4* p = (const float4*)(x + (size_t)i * 8);
        float4 v0 = p[0], v1 = p[1];
        int4 w = make_int4(pack2(f2bf(v0.x), f2bf(v0.y)), pack2(f2bf(v0.z), f2bf(v0.w)),
                           pack2(f2bf(v1.x), f2bf(v1.y)), pack2(f2bf(v1.z), f2bf(v1.w)));
        *(int4*)(xb + (size_t)i * 8) = w;
    }
}

// ---------------- tall-skinny bf16 MFMA GEMM ----------------
// Tout[m][bn+j] = bf16((A[m,:] @ Bt[bn+j,:]) * dinv[m]).
// B slice (64 cols x K) staged in LDS ONCE; A fragments global->VGPR direct.
// No barriers in K-loop. Wave: 64 rows x 64 cols. Grid: (npad/256, N/64).

template<int K>
__global__ __launch_bounds__(256, 2) void gemm_skinny_kernel(
        const short* __restrict__ A,     // [npad][K]
        const short* __restrict__ Bt,    // [N][K]
        const float* __restrict__ dinv,  // [npad]
        short* __restrict__ Tout, int ldt) {
    constexpr int BSTR = K + 8;
    __shared__ short Bs[64 * BSTR];

    const int tid = threadIdx.x;
    const int lane = tid & 63;
    const int wid = tid >> 6;
    const int l15 = lane & 15;
    const int quad = lane >> 4;
    const int q8 = quad * 8;
    const int bn = blockIdx.y * 64;
    const int row0 = blockIdx.x * 256 + wid * 64;

    {
        constexpr int TOT16 = 64 * K / 8;
#pragma unroll
        for (int i = tid; i < TOT16; i += 256) {
            int r = i / (K / 8);
            int c = (i % (K / 8)) * 8;
            *(int4*)&Bs[r * BSTR + c] = *(const int4*)&Bt[(size_t)(bn + r) * K + c];
        }
    }
    __syncthreads();

    f32x4v acc[4][4];
#pragma unroll
    for (int i = 0; i < 4; ++i)
#pragma unroll
        for (int j = 0; j < 4; ++j) acc[i][j] = (f32x4v){0.f, 0.f, 0.f, 0.f};

    const short* aBase = A + (size_t)(row0 + l15) * K + q8;

#pragma unroll
    for (int ks = 0; ks < K / 32; ++ks) {
        bfrag8 af[4], bf[4];
#pragma unroll
        for (int mt = 0; mt < 4; ++mt)
            af[mt] = *(const bfrag8*)(aBase + (size_t)mt * 16 * K + ks * 32);
#pragma unroll
        for (int nt = 0; nt < 4; ++nt)
            bf[nt] = *(const bfrag8*)&Bs[(nt * 16 + l15) * BSTR + ks * 32 + q8];
#pragma unroll
        for (int mt = 0; mt < 4; ++mt)
#pragma unroll
            for (int nt = 0; nt < 4; ++nt)
                acc[mt][nt] = __builtin_amdgcn_mfma_f32_16x16x32_bf16(af[mt], bf[nt], acc[mt][nt], 0, 0, 0);
    }

#pragma unroll
    for (int mt = 0; mt < 4; ++mt) {
#pragma unroll
        for (int r = 0; r < 4; ++r) {
            int grow = row0 + mt * 16 + quad * 4 + r;
            float di = dinv[grow];
            short* outp = Tout + (size_t)grow * ldt + bn + l15;
#pragma unroll
            for (int nt = 0; nt < 4; ++nt)
                outp[nt * 16] = f2bf(acc[mt][nt][r] * di);
        }
    }
}

// ---------------- Aggregation, C=256: one wave per node, 1 edge per wave-load ----------------

template<bool WB>
__global__ __launch_bounds__(256) void agg256_kernel(
        const short* __restrict__ hn, const float* __restrict__ dinv,
        const int* __restrict__ offs, const int* __restrict__ csr,
        const float* __restrict__ bias, float* __restrict__ out,
        short* __restrict__ hb, int coloff, int n) {
    int node = blockIdx.x * 4 + (threadIdx.x >> 6);
    if (node >= n) return;
    int lane = threadIdx.x & 63;
    const short* base = hn + lane * 4;

    float acc[4] = {0.f, 0.f, 0.f, 0.f};
    int beg = offs[node], end = offs[node + 1];
    int e = beg;
    for (; e + 8 <= end; e += 8) {
        short4 r[8];
#pragma unroll
        for (int j = 0; j < 8; ++j)
            r[j] = *(const short4*)(base + (size_t)csr[e + j] * 256);
#pragma unroll
        for (int j = 0; j < 8; ++j) {
            acc[0] += bf2f(r[j].x); acc[1] += bf2f(r[j].y);
            acc[2] += bf2f(r[j].z); acc[3] += bf2f(r[j].w);
        }
    }
    for (; e < end; ++e) {
        short4 a = *(const short4*)(base + (size_t)csr[e] * 256);
        acc[0] += bf2f(a.x); acc[1] += bf2f(a.y); acc[2] += bf2f(a.z); acc[3] += bf2f(a.w);
    }
    {   // self loop
        short4 a = *(const short4*)(base + (size_t)node * 256);
        acc[0] += bf2f(a.x); acc[1] += bf2f(a.y); acc[2] += bf2f(a.z); acc[3] += bf2f(a.w);
    }

    float di = dinv[node];
    float res[4];
#pragma unroll
    for (int v = 0; v < 4; ++v)
        res[v] = fmaxf(fmaf(di, acc[v], bias[lane * 4 + v]), 0.f);

    *(float4*)(out + (size_t)node * 512 + coloff + lane * 4) =
        make_float4(res[0], res[1], res[2], res[3]);
    if (WB) {
        int2 w = make_int2(pack2(f2bf(res[0]), f2bf(res[1])), pack2(f2bf(res[2]), f2bf(res[3])));
        *(int2*)(hb + (size_t)node * 256 + lane * 4) = w;
    }
}

// ---------------- Aggregation, C=128: half-wave per edge, 2 edges per wave-load ----------------
// lanes 0-31 gather even-offset edges, lanes 32-63 odd; shfl_xor(32) combine; half 0 writes.

template<bool WB>
__global__ __launch_bounds__(256) void agg128_kernel(
        const short* __restrict__ hn, const float* __restrict__ dinv,
        const int* __restrict__ offs, const int* __restrict__ csr,
        const float* __restrict__ bias, float* __restrict__ out,
        short* __restrict__ hb, int coloff, int n) {
    int node = blockIdx.x * 4 + (threadIdx.x >> 6);
    if (node >= n) return;
    int lane = threadIdx.x & 63;
    int hl = lane & 31;       // half-lane: channel group
    int half = lane >> 5;     // which edge of the pair
    const short* base = hn + hl * 4;   // 32 lanes x 4 shorts = 128 ch

    float acc[4] = {0.f, 0.f, 0.f, 0.f};
    int beg = offs[node], end = offs[node + 1];
    int cnt = end - beg;
    int pairs = cnt >> 1;

    int j = 0;
    for (; j + 4 <= pairs; j += 4) {
        short4 r[4];
#pragma unroll
        for (int u = 0; u < 4; ++u) {
            int s = csr[beg + 2 * (j + u) + half];
            r[u] = *(const short4*)(base + (size_t)s * 128);
        }
#pragma unroll
        for (int u = 0; u < 4; ++u) {
            acc[0] += bf2f(r[u].x); acc[1] += bf2f(r[u].y);
            acc[2] += bf2f(r[u].z); acc[3] += bf2f(r[u].w);
        }
    }
    for (; j < pairs; ++j) {
        int s = csr[beg + 2 * j + half];
        short4 r = *(const short4*)(base + (size_t)s * 128);
        acc[0] += bf2f(r.x); acc[1] += bf2f(r.y); acc[2] += bf2f(r.z); acc[3] += bf2f(r.w);
    }
    // leftover odd edge (if any) + self-loop, split across halves
    int extra;
    if (cnt & 1) extra = (half == 0) ? csr[beg + 2 * pairs] : node;
    else         extra = (half == 0) ? node : -1;
    if (extra >= 0) {
        short4 r = *(const short4*)(base + (size_t)extra * 128);
        acc[0] += bf2f(r.x); acc[1] += bf2f(r.y); acc[2] += bf2f(r.z); acc[3] += bf2f(r.w);
    }

    // combine halves
#pragma unroll
    for (int v = 0; v < 4; ++v) acc[v] += __shfl_xor(acc[v], 32);

    if (half == 0) {
        float di = dinv[node];
        float res[4];
#pragma unroll
        for (int v = 0; v < 4; ++v)
            res[v] = fmaxf(fmaf(di, acc[v], bias[hl * 4 + v]), 0.f);
        *(float4*)(out + (size_t)node * 512 + coloff + hl * 4) =
            make_float4(res[0], res[1], res[2], res[3]);
        if (WB) {
            int2 w = make_int2(pack2(f2bf(res[0]), f2bf(res[1])), pack2(f2bf(res[2]), f2bf(res[3])));
            *(int2*)(hb + (size_t)node * 128 + hl * 4) = w;
        }
    }
}

// ---------------- launch ----------------

extern "C" void kernel_launch(void* const* d_in, const int* in_sizes, int n_in,
                              void* d_out, int out_size, void* d_ws, size_t ws_size,
                              hipStream_t stream) {
    const float* x  = (const float*)d_in[0];
    const int*   ei = (const int*)d_in[1];
    const float* W1 = (const float*)d_in[2];
    const float* b1 = (const float*)d_in[3];
    const float* W2 = (const float*)d_in[4];
    const float* b2 = (const float*)d_in[5];
    const float* W3 = (const float*)d_in[6];
    const float* b3 = (const float*)d_in[7];

    const int IN_C = 256, H2 = 256, H1 = 128, OUT_C = 128;
    int n = in_sizes[0] / IN_C;   // 50000
    int E = in_sizes[1] / 2;      // 800000
    const int* src = ei;
    const int* dst = ei + E;

    int sb = (n + 255) / 256;     // 196
    int npad = sb * 256;          // 50176

    char* ws = (char*)d_ws;
    auto carve = [&](size_t bytes) { char* p = ws; ws += (bytes + 255) & ~(size_t)255; return p; };
    int*   deg    = (int*)  carve((size_t)n * 4);
    int*   offs   = (int*)  carve(((size_t)n + 1) * 4);
    int*   cursor = (int*)  carve((size_t)n * 4);
    float* dinv   = (float*)carve((size_t)npad * 4);
    int*   csr    = (int*)  carve((size_t)E * 4);
    int*   bsums  = (int*)  carve(256 * 4);
    short* Wt1    = (short*)carve((size_t)IN_C * H2 * 2);
    short* Wt2    = (short*)carve((size_t)H2 * H1 * 2);
    short* Wt3    = (short*)carve((size_t)H1 * OUT_C * 2);
    short* t      = (short*)carve((size_t)npad * 256 * 2);
    short* inb    = (short*)carve((size_t)npad * 256 * 2);  // xb -> h1b -> h2b

    float* out = (float*)d_out;
    int nblk = (n + 255) / 256;

    hipMemsetAsync(deg, 0, (size_t)n * sizeof(int), stream);
    deg_count_kernel<<<(E + 255) / 256, 256, 0, stream>>>(dst, E, deg);
    block_sum_kernel<<<nblk, 256, 0, stream>>>(deg, n, bsums);
    scan_bsums_kernel<<<1, 256, 0, stream>>>(bsums, nblk, offs, n);
    scan_final_kernel<<<nblk, 256, 0, stream>>>(deg, n, bsums, offs, cursor, dinv);
    csr_fill_kernel<<<(E + 255) / 256, 256, 0, stream>>>(src, dst, E, cursor, csr);

    prep_w_kernel<<<(65536 + 32768 + 16384 + 255) / 256, 256, 0, stream>>>(W1, Wt1, W2, Wt2, W3, Wt3);

    int total8 = n * IN_C / 8;
    x2b_kernel<<<(total8 + 255) / 256, 256, 0, stream>>>(x, inb, total8);

    // Layer 1
    gemm_skinny_kernel<256><<<dim3(sb, H2 / 64), 256, 0, stream>>>(inb, Wt1, dinv, t, H2);
    agg256_kernel<true><<<(n + 3) / 4, 256, 0, stream>>>(t, dinv, offs, csr, b1, out, inb, 0, n);

    // Layer 2 (K=256 -> C=128)
    gemm_skinny_kernel<256><<<dim3(sb, H1 / 64), 256, 0, stream>>>(inb, Wt2, dinv, t, H1);
    agg128_kernel<true><<<(n + 3) / 4, 256, 0, stream>>>(t, dinv, offs, csr, b2, out, inb, H2, n);

    // Layer 3 (K=128 -> C=128)
    gemm_skinny_kernel<128><<<dim3(sb, OUT_C / 64), 256, 0, stream>>>(inb, Wt3, dinv, t, OUT_C);
    agg128_kernel<false><<<(n + 3) / 4, 256, 0, stream>>>(t, dinv, offs, csr, b3, out, nullptr, H2 + H1, n);
}